// Round 4
// baseline (571.132 us; speedup 1.0000x reference)
//
#include <hip/hip_runtime.h>
#include <math.h>

#define BSZ 4
#define DM 256
#define HH 256
#define WW 256
#define LL 256
#define DI 512
#define NBL (BSZ * LL)  // 1024

// ---------------- phase A: x_h = mean over W ----------------
__global__ __launch_bounds__(256) void k_mean_w(const float* __restrict__ x0,
                                                float* __restrict__ xseq) {
    int wave = (blockIdx.x * blockDim.x + threadIdx.x) >> 6;
    int lane = threadIdx.x & 63;
    int b = wave >> 16;
    int d = (wave >> 8) & 255;
    int h = wave & 255;
    const float4* row = (const float4*)(x0 + (size_t)wave * WW);
    float4 v = row[lane];
    float s = v.x + v.y + v.z + v.w;
#pragma unroll
    for (int m = 32; m >= 1; m >>= 1) s += __shfl_xor(s, m);
    if (lane == 0) xseq[((size_t)(b * LL) + h) * DM + d] = s * (1.0f / WW);
}

// ---------------- fp32 GEMM: C[M,N] = A[M,K] * B[N,K]^T, tile 32x64 ----------------
__global__ __launch_bounds__(256) void k_gemm_nt32(const float* __restrict__ A,
                                                   const float* __restrict__ Bw,
                                                   float* __restrict__ C,
                                                   int M, int N, int K) {
    __shared__ float As[16][32];
    __shared__ float Bs[16][64];
    int tid = threadIdx.x;
    int tx = tid & 15, ty = tid >> 4;   // n-quad, m-pair
    int n0 = blockIdx.x * 64;
    int m0 = blockIdx.y * 32;
    int lr = tid >> 2;
    int lk = (tid & 3) * 4;

    float acc[2][4];
#pragma unroll
    for (int i = 0; i < 2; ++i)
#pragma unroll
        for (int j = 0; j < 4; ++j) acc[i][j] = 0.0f;

    for (int k0 = 0; k0 < K; k0 += 16) {
        float4 bv = *(const float4*)(Bw + (size_t)(n0 + lr) * K + k0 + lk);
        float4 av;
        if (tid < 128) av = *(const float4*)(A + (size_t)(m0 + lr) * K + k0 + lk);
        __syncthreads();
        Bs[lk + 0][lr] = bv.x; Bs[lk + 1][lr] = bv.y; Bs[lk + 2][lr] = bv.z; Bs[lk + 3][lr] = bv.w;
        if (tid < 128) {
            As[lk + 0][lr] = av.x; As[lk + 1][lr] = av.y; As[lk + 2][lr] = av.z; As[lk + 3][lr] = av.w;
        }
        __syncthreads();
#pragma unroll
        for (int kk = 0; kk < 16; ++kk) {
            float a0 = As[kk][ty * 2 + 0];
            float a1 = As[kk][ty * 2 + 1];
            float4 bf = *(const float4*)(&Bs[kk][tx << 2]);
            float bb[4] = {bf.x, bf.y, bf.z, bf.w};
#pragma unroll
            for (int j = 0; j < 4; ++j) {
                acc[0][j] = fmaf(a0, bb[j], acc[0][j]);
                acc[1][j] = fmaf(a1, bb[j], acc[1][j]);
            }
        }
    }
#pragma unroll
    for (int i = 0; i < 2; ++i)
#pragma unroll
        for (int j = 0; j < 4; ++j)
            C[(size_t)(m0 + ty * 2 + i) * N + n0 + (tx << 2) + j] = acc[i][j];
}

// ---------------- fused conv+silu+xproj: one block per (b,l) ----------------
__global__ __launch_bounds__(256) void k_mid(const float* __restrict__ xz,
                                             const float* __restrict__ cw,
                                             const float* __restrict__ cb,
                                             const float* __restrict__ xpw,
                                             float* __restrict__ xx,
                                             float* __restrict__ xdbl) {
    __shared__ float xs[DI];
    __shared__ float pr[256];
    int bl = blockIdx.x;
    int b = bl >> 8, l = bl & 255;
    int tid = threadIdx.x;

#pragma unroll
    for (int c = 0; c < 2; ++c) {
        int d = tid + 256 * c;
        float4 w4 = *(const float4*)(cw + d * 4);
        float wk[4] = {w4.x, w4.y, w4.z, w4.w};
        float acc = cb[d];
#pragma unroll
        for (int k = 0; k < 4; ++k) {
            int ls = l + k - 3;
            float v = (ls >= 0) ? xz[((size_t)(b * LL + ls)) * (2 * DI) + d] : 0.0f;
            acc = fmaf(wk[k], v, acc);
        }
        float v = acc / (1.0f + expf(-acc));
        xs[d] = v;
        xx[(size_t)bl * DI + d] = v;
    }
    __syncthreads();

    int e = tid >> 2, c = tid & 3;
    float a = 0.0f;
    if (e < 48) {
        const float4* xv = (const float4*)(xs + c * 128);
        const float4* wv = (const float4*)(xpw + (size_t)e * DI + c * 128);
#pragma unroll 8
        for (int q = 0; q < 32; ++q) {
            float4 x4 = xv[q], p4 = wv[q];
            a = fmaf(x4.x, p4.x, a);
            a = fmaf(x4.y, p4.y, a);
            a = fmaf(x4.z, p4.z, a);
            a = fmaf(x4.w, p4.w, a);
        }
    }
    pr[tid] = a;
    __syncthreads();
    if (tid < 48)
        xdbl[(size_t)bl * 48 + tid] = pr[4 * tid] + pr[4 * tid + 1] + pr[4 * tid + 2] + pr[4 * tid + 3];
}

// ---------------- selective scan: one block per (b,d); 4 waves x 4 states ----------------
__global__ __launch_bounds__(256) void k_scan(const float* __restrict__ xx,
                                              const float* __restrict__ xdbl,
                                              const float* __restrict__ xz,
                                              const float* __restrict__ Alog,
                                              const float* __restrict__ Dp,
                                              const float* __restrict__ dtw,
                                              const float* __restrict__ dtb,
                                              float* __restrict__ yg) {
    __shared__ float yred[4][LL];
    __shared__ float us[LL];
    int tid = threadIdx.x;
    int lane = tid & 63, w = tid >> 6;
    int seq = blockIdx.x;              // b*DI + d
    int d = seq & (DI - 1), b = seq >> 9;
    int l0 = lane * 4;

    const float* xd0 = xdbl + ((size_t)(b * LL) + l0) * 48;

    const float* wr = dtw + d * 16;
    float4 w0 = *(const float4*)(wr + 0);
    float4 w1 = *(const float4*)(wr + 4);
    float4 w2 = *(const float4*)(wr + 8);
    float4 w3 = *(const float4*)(wr + 12);
    float bias = dtb[d];

    float dt[4], u[4], dtu[4], P[4];
#pragma unroll
    for (int i = 0; i < 4; ++i) {
        const float* xr = xd0 + i * 48;
        float4 a0 = *(const float4*)(xr + 0);
        float4 a1 = *(const float4*)(xr + 4);
        float4 a2 = *(const float4*)(xr + 8);
        float4 a3 = *(const float4*)(xr + 12);
        float acc = bias;
        acc = fmaf(a0.x, w0.x, acc); acc = fmaf(a0.y, w0.y, acc);
        acc = fmaf(a0.z, w0.z, acc); acc = fmaf(a0.w, w0.w, acc);
        acc = fmaf(a1.x, w1.x, acc); acc = fmaf(a1.y, w1.y, acc);
        acc = fmaf(a1.z, w1.z, acc); acc = fmaf(a1.w, w1.w, acc);
        acc = fmaf(a2.x, w2.x, acc); acc = fmaf(a2.y, w2.y, acc);
        acc = fmaf(a2.z, w2.z, acc); acc = fmaf(a2.w, w2.w, acc);
        acc = fmaf(a3.x, w3.x, acc); acc = fmaf(a3.y, w3.y, acc);
        acc = fmaf(a3.z, w3.z, acc); acc = fmaf(a3.w, w3.w, acc);
        dt[i] = (acc > 20.0f) ? acc : log1pf(expf(acc));
        u[i] = xx[((size_t)(b * LL) + l0 + i) * DI + d];
        dtu[i] = dt[i] * u[i];
    }

    P[0] = dt[0]; P[1] = P[0] + dt[1]; P[2] = P[1] + dt[2]; P[3] = P[2] + dt[3];
    float s = P[3];
#pragma unroll
    for (int off = 1; off < 64; off <<= 1) {
        float t = __shfl_up(s, off);
        if (lane >= off) s += t;
    }
    float base = s - P[3];
    float dt_end = __shfl(s, 63);
    float Dtc[4];
#pragma unroll
    for (int i = 0; i < 4; ++i) Dtc[i] = P[i] + base;

    if (w == 0) {
#pragma unroll
        for (int i = 0; i < 4; ++i) us[l0 + i] = u[i];
    }

    float4 Al = *(const float4*)(Alog + d * 16 + 4 * w);
    float A[4] = {-expf(Al.x), -expf(Al.y), -expf(Al.z), -expf(Al.w)};
    float Bv[4][4], Cv[4][4];
#pragma unroll
    for (int i = 0; i < 4; ++i) {
        float4 bq = *(const float4*)(xd0 + i * 48 + 16 + 4 * w);
        float4 cq = *(const float4*)(xd0 + i * 48 + 32 + 4 * w);
        Bv[i][0] = bq.x; Bv[i][1] = bq.y; Bv[i][2] = bq.z; Bv[i][3] = bq.w;
        Cv[i][0] = cq.x; Cv[i][1] = cq.y; Cv[i][2] = cq.z; Cv[i][3] = cq.w;
    }

    float y[4] = {0.0f, 0.0f, 0.0f, 0.0f};
#pragma unroll
    for (int c = 0; c < 4; ++c) {
        float Ac = A[c];
        float dAc[4], t[4];
#pragma unroll
        for (int i = 0; i < 4; ++i) {
            dAc[i] = expf(Ac * (dt_end - Dtc[i]));
            t[i] = dtu[i] * Bv[i][c] * dAc[i];
        }
        float p0 = t[0], p1 = p0 + t[1], p2 = p1 + t[2], p3 = p2 + t[3];
        float ss = p3;
#pragma unroll
        for (int off = 1; off < 64; off <<= 1) {
            float tt = __shfl_up(ss, off);
            if (lane >= off) ss += tt;
        }
        float baseT = ss - p3;
        y[0] += (p0 + baseT) / (dAc[0] + 1e-12f) * Cv[0][c];
        y[1] += (p1 + baseT) / (dAc[1] + 1e-12f) * Cv[1][c];
        y[2] += (p2 + baseT) / (dAc[2] + 1e-12f) * Cv[2][c];
        y[3] += (p3 + baseT) / (dAc[3] + 1e-12f) * Cv[3][c];
    }
#pragma unroll
    for (int i = 0; i < 4; ++i) yred[w][l0 + i] = y[i];
    __syncthreads();

    int l = tid;
    float ysum = yred[0][l] + yred[1][l] + yred[2][l] + yred[3][l];
    float yv = fmaf(us[l], Dp[d], ysum);
    float res = xz[((size_t)(b * LL) + l) * (2 * DI) + DI + d];
    yg[((size_t)(b * LL) + l) * DI + d] = yv * (res / (1.0f + expf(-res)));
}

// ---------------- phase C: x_w[b,w,dm] = mean_h( m[b,h,dm] * x0[b,dm,h,w] ) ----------------
// unrolled x8 over h for memory-level parallelism
__global__ __launch_bounds__(256) void k_fuse_mean_h(const float* __restrict__ m,
                                                     const float* __restrict__ x0,
                                                     float* __restrict__ xw) {
    int bd = blockIdx.x;
    int b = bd >> 8, d = bd & 255;
    int w = threadIdx.x;
    __shared__ float ms[HH];
    ms[w] = m[((size_t)(b * LL) + w) * DM + d];
    __syncthreads();
    const float* xrow = x0 + (size_t)bd * HH * WW;
    float a0 = 0.0f, a1 = 0.0f, a2 = 0.0f, a3 = 0.0f;
    for (int h = 0; h < HH; h += 8) {
        float xv[8];
#pragma unroll
        for (int j = 0; j < 8; ++j) xv[j] = xrow[(size_t)(h + j) * WW + w];
        a0 = fmaf(ms[h + 0], xv[0], a0);
        a1 = fmaf(ms[h + 1], xv[1], a1);
        a2 = fmaf(ms[h + 2], xv[2], a2);
        a3 = fmaf(ms[h + 3], xv[3], a3);
        a0 = fmaf(ms[h + 4], xv[4], a0);
        a1 = fmaf(ms[h + 5], xv[5], a1);
        a2 = fmaf(ms[h + 6], xv[6], a2);
        a3 = fmaf(ms[h + 7], xv[7], a3);
    }
    float acc = (a0 + a1) + (a2 + a3);
    xw[((size_t)(b * LL) + w) * DM + d] = acc * (1.0f / HH);
}

// ---------------- phase E fused: out[b,d,h,w] = mw[b,w,dm=d] * x0[b,d,h,w] ----------------
// one block per (b,d); gather m-row into LDS once, stream 256x256 tile
__global__ __launch_bounds__(256) void k_final(const float* __restrict__ mw,
                                               const float* __restrict__ x0,
                                               float* __restrict__ out) {
    __shared__ float ms[WW];
    int bd = blockIdx.x;
    int b = bd >> 8, d = bd & 255;
    int tid = threadIdx.x;
    ms[tid] = mw[((size_t)(b * LL) + tid) * DM + d];
    __syncthreads();

    int w4 = tid & 63;      // float4 index along w
    int hq = tid >> 6;      // 0..3
    float4 mv = *(const float4*)(ms + (w4 << 2));
    const float4* xin = (const float4*)(x0 + (size_t)bd * HH * WW);
    float4* oout = (float4*)(out + (size_t)bd * HH * WW);
#pragma unroll 4
    for (int hi = 0; hi < 64; ++hi) {
        int h = hi * 4 + hq;
        size_t idx = (size_t)h * 64 + w4;
        float4 xv = xin[idx];
        float4 o;
        o.x = mv.x * xv.x;
        o.y = mv.y * xv.y;
        o.z = mv.z * xv.z;
        o.w = mv.w * xv.w;
        oout[idx] = o;
    }
}

extern "C" void kernel_launch(void* const* d_in, const int* in_sizes, int n_in,
                              void* d_out, int out_size, void* d_ws, size_t ws_size,
                              hipStream_t stream) {
    const float* x0     = (const float*)d_in[0];
    const float* in_w   = (const float*)d_in[1];
    const float* conv_w = (const float*)d_in[2];
    const float* conv_b = (const float*)d_in[3];
    const float* xproj_w= (const float*)d_in[4];
    const float* dt_w   = (const float*)d_in[5];
    const float* dt_b   = (const float*)d_in[6];
    const float* A_log  = (const float*)d_in[7];
    const float* Dp     = (const float*)d_in[8];
    const float* out_w  = (const float*)d_in[9];
    float* out = (float*)d_out;

    float* S0   = (float*)d_ws;            // NBL*DM
    float* S1   = S0 + 262144;
    float* S2   = S1 + 262144;
    float* xz   = S2 + 262144;             // NBL*2DI
    float* xx   = xz + 1048576;            // NBL*DI
    float* xdbl = xx + 524288;             // NBL*48
    float* yg   = xdbl + 49152;            // NBL*DI

    auto run_block = [&](const float* in, float* outb, int layer) {
        k_gemm_nt32<<<dim3((2 * DI) / 64, NBL / 32), 256, 0, stream>>>(
            in, in_w + (size_t)layer * 2 * DI * DM, xz, NBL, 2 * DI, DM);
        k_mid<<<NBL, 256, 0, stream>>>(
            xz, conv_w + (size_t)layer * DI * 4, conv_b + (size_t)layer * DI,
            xproj_w + (size_t)layer * 48 * DI, xx, xdbl);
        k_scan<<<BSZ * DI, 256, 0, stream>>>(
            xx, xdbl, xz, A_log + (size_t)layer * DI * 16, Dp + (size_t)layer * DI,
            dt_w + (size_t)layer * DI * 16, dt_b + (size_t)layer * DI, yg);
        k_gemm_nt32<<<dim3(DM / 64, NBL / 32), 256, 0, stream>>>(
            yg, out_w + (size_t)layer * DM * DI, outb, NBL, DM, DI);
    };

    k_mean_w<<<65536, 256, 0, stream>>>(x0, S0);
    run_block(S0, S1, 0);
    run_block(S1, S2, 1);
    k_fuse_mean_h<<<BSZ * DM, 256, 0, stream>>>(S2, x0, S0);
    run_block(S0, S1, 0);
    run_block(S1, S2, 1);
    k_final<<<BSZ * DM, 256, 0, stream>>>(S2, x0, out);
}